// Round 4
// baseline (189.461 us; speedup 1.0000x reference)
//
#include <hip/hip_runtime.h>
#include <hip/hip_bf16.h>

typedef __bf16 bf16x8 __attribute__((ext_vector_type(8)));
typedef float  f32x4  __attribute__((ext_vector_type(4)));

#define NEG_BIG (-1e10f)

constexpr int FUSED_N = 4 * 32 * 32 * 256;  // 1048576

// ---------------------------------------------------------------------------
// fp32 inputs, no fp32 MFMA on CDNA4: split x = hi + lo (bf16 RNE + residual),
// scores ~= Ah*Bh + Ah*Bl + Al*Bh (drop lo*lo). Verified r2-r5.
// r3/r5 lesson: spill tripwire = WRITE_SIZE above the exact 69,636 KB floor.
// r5 lesson: total-minus-main ~90 us is fixed harness overhead.
// r6 lesson: each async_ld16 covers 2 rows; 64 rows = 32 insts.
// r7: 512-thread blocks, 8 waves share the P tile, one j per wave.
// r8: __launch_bounds__(512,4) = 4 waves/EU = 128-reg TOTAL budget; acc took
//   64 AGPR -> 64 arch cap -> 38MB spill. (512,2) leaves allocator uncapped.
// r9: ng-half split (acc[4][2]) to shrink live set.
// r10 lesson (r0-r3 triangulated): residency is BLOCK-granular with a
//   combined arch+AGPR <=128 threshold (per-SIMD pool 512, block=2 waves/SIMD):
//     r0 108+64=172 -> 1 blk (19.6%) | r1 64+64=128 -> 2 blk (36%, spilled)
//     r2  84+64=148 -> 1 blk (20%)   | r3 92+64=156 -> 1 blk (20.5%)
//   r3's `#pragma unroll` on nh let the scheduler keep BOTH acc banks live
//   (AGPR stayed 64) -> paid split overhead, got no occupancy. Fix here:
//   `#pragma unroll 1` on nh -> one acc[4][2] bank (32 AGPR) live,
//   92+32=124 <= 128 -> 2 blocks/CU. Single-variable change vs r3.
// ---------------------------------------------------------------------------

// Async 16B global->LDS (DMA). Lane L lands at wave-uniform base + 16*L.
__device__ __forceinline__ void async_ld16(const void* g, void* l) {
    __builtin_amdgcn_global_load_lds(
        (const __attribute__((address_space(1))) void*)g,
        (__attribute__((address_space(3))) void*)l, 16, 0, 0);
}

// 16row x 32granule (16x256 bf16) tile for prep.
__device__ __forceinline__ int swzp(int row, int g) {
    return (row * 32 + (g ^ row)) * 8;   // row in [0,16)
}

// W fp32 -> hi/lo bf16 planes. 64 blocks x 256 threads x 4 elems.
__global__ __launch_bounds__(256) void convw_kernel(
    const float* __restrict__ W, __bf16* __restrict__ Wh, __bf16* __restrict__ Wl) {
    int idx = blockIdx.x * 256 + threadIdx.x;  // 0..16383
    float4 v = ((const float4*)W)[idx];
    float f[4] = {v.x, v.y, v.z, v.w};
    union { __bf16 b[4]; uint2 u; } H, L;
#pragma unroll
    for (int k = 0; k < 4; ++k) {
        __bf16 h = (__bf16)f[k];
        H.b[k] = h;
        L.b[k] = (__bf16)(f[k] - (float)h);
    }
    *(uint2*)&Wh[idx * 4] = H.u;
    *(uint2*)&Wl[idx * 4] = L.u;
}

// ---------------------------------------------------------------------------
// prep: convert 16 X rows -> Xh/Xl planes (global + LDS) and compute
// P = X @ W^T (split-3) -> Ph/Pl. 512 blocks; wave w handles col group w.
// ---------------------------------------------------------------------------
__global__ __launch_bounds__(256, 2) void prep_kernel(
    const float* __restrict__ Xf,
    const __bf16* __restrict__ Wh, const __bf16* __restrict__ Wl,
    __bf16* __restrict__ XhG, __bf16* __restrict__ XlG,
    __bf16* __restrict__ Ph, __bf16* __restrict__ Pl) {
    __shared__ __align__(16) __bf16 sXh[16 * 256];   // 8 KB
    __shared__ __align__(16) __bf16 sXl[16 * 256];   // 8 KB
    const int tid = threadIdx.x, rb = blockIdx.x;    // rows rb*16..rb*16+15

#pragma unroll
    for (int it = 0; it < 2; ++it) {
        int idx = it * 256 + tid;          // 512 granules
        int row = idx >> 5, g = idx & 31;
        const float* p = Xf + (rb * 16 + row) * 256 + g * 8;
        float4 v0 = *(const float4*)p;
        float4 v1 = *(const float4*)(p + 4);
        float f[8] = {v0.x, v0.y, v0.z, v0.w, v1.x, v1.y, v1.z, v1.w};
        union { __bf16 b[8]; uint4 u; } H, L;
#pragma unroll
        for (int k = 0; k < 8; ++k) {
            __bf16 h = (__bf16)f[k];
            H.b[k] = h;
            L.b[k] = (__bf16)(f[k] - (float)h);
        }
        int go = (rb * 16 + row) * 256 + g * 8;
        *(uint4*)&XhG[go] = H.u;
        *(uint4*)&XlG[go] = L.u;
        int o = swzp(row, g);
        *(uint4*)&sXh[o] = H.u;
        *(uint4*)&sXl[o] = L.u;
    }
    __syncthreads();

    const int lane = tid & 63, wave = tid >> 6, m = lane & 15, quad = lane >> 4;
    bf16x8 Ah[8], Al[8];
#pragma unroll
    for (int k0 = 0; k0 < 8; ++k0) {
        int o = swzp(m, k0 * 4 + quad);
        Ah[k0] = *(const bf16x8*)&sXh[o];
        Al[k0] = *(const bf16x8*)&sXl[o];
    }
    f32x4 acc[4];
    const f32x4 z = {0.f, 0.f, 0.f, 0.f};
#pragma unroll
    for (int n = 0; n < 4; ++n) acc[n] = z;
#pragma unroll
    for (int k0 = 0; k0 < 8; ++k0) {
#pragma unroll
        for (int n = 0; n < 4; ++n) {
            const int gcol = wave * 64 + n * 16 + m;
            const int wo = gcol * 256 + k0 * 32 + quad * 8;
            bf16x8 bh = *(const bf16x8*)&Wh[wo];
            bf16x8 bl = *(const bf16x8*)&Wl[wo];
            acc[n] = __builtin_amdgcn_mfma_f32_16x16x32_bf16(Ah[k0], bh, acc[n], 0, 0, 0);
            acc[n] = __builtin_amdgcn_mfma_f32_16x16x32_bf16(Ah[k0], bl, acc[n], 0, 0, 0);
            acc[n] = __builtin_amdgcn_mfma_f32_16x16x32_bf16(Al[k0], bh, acc[n], 0, 0, 0);
        }
    }
#pragma unroll
    for (int n = 0; n < 4; ++n)
#pragma unroll
        for (int r = 0; r < 4; ++r) {
            int row = rb * 16 + quad * 4 + r;
            int col = wave * 64 + n * 16 + m;
            float v = acc[n][r];
            __bf16 h = (__bf16)v;
            Ph[row * 256 + col] = h;
            Pl[row * 256 + col] = (__bf16)(v - (float)h);
        }
}

// ---------------------------------------------------------------------------
// main: 512 blocks = (b, i, jq), 512 threads = 8 waves. Stage P(b,i) hi/lo
// (64 KB, swizzled) via async DMA; ONE barrier; each wave owns j = jq*8+wave
// and computes its 64x64 score tile in TWO strictly-sequential ng-half
// passes (unroll 1!) so only one acc[4][2] bank (32 AGPR) is ever live ->
// combined regs ~124 <= 128 -> 2 blocks/CU resident (16 waves/CU). B frags
// stream from global (L2-hot, each column fetched once); A frags re-read
// from LDS per pass. Epilogue per pass is wave-local; aself row in LDS.
// ---------------------------------------------------------------------------
__global__ __launch_bounds__(512, 2) void main_kernel(
    const float* __restrict__ Xf, const float* __restrict__ maskf,
    const float* __restrict__ aselff,
    const __bf16* __restrict__ XhG, const __bf16* __restrict__ XlG,
    const __bf16* __restrict__ PhG, const __bf16* __restrict__ PlG,
    float* __restrict__ out) {
    __shared__ __align__(16) __bf16 sPh[64 * 256];   // 32 KB
    __shared__ __align__(16) __bf16 sPl[64 * 256];   // 32 KB
    __shared__ float sW[8][64];                      // 2 KB, wave-private rows
    __shared__ float sAs[64];                        // 256 B, aself row (i)
    const int tid = threadIdx.x;
    const int jq = blockIdx.x & 3;
    const int i  = (blockIdx.x >> 2) & 31;
    const int b  = blockIdx.x >> 7;
    const int lane = tid & 63, wave = tid >> 6, m = lane & 15, quad = lane >> 4;

    // Stage P(b,i) hi/lo. Each inst covers rows 2*insti..+1 (64 lanes x 16B);
    // 64 rows = 32 insts = 4 per wave. Slot (row,gs) gets granule gs^(row&15).
    const int pbase = (b * 32 + i) * 16384;
    {
        const int rowhalf = lane >> 5;     // 0..1
        const int gslot = lane & 31;
#pragma unroll
        for (int it = 0; it < 4; ++it) {
            const int insti = wave * 4 + it;           // 0..31
            const int row = insti * 2 + rowhalf;       // 0..63
            const int g = gslot ^ (row & 15);
            const int src = pbase + row * 256 + g * 8;
            async_ld16(&PhG[src], &sPh[insti * 512]);
            async_ld16(&PlG[src], &sPl[insti * 512]);
        }
    }

    // aself row for block-constant i -> LDS (broadcast reads in epilogue).
    if (tid < 64) sAs[tid] = aselff[(b * 32 + i) * 64 + tid];

    __syncthreads();   // DMA drained; the ONLY barrier

    const int j = jq * 8 + wave;
    const int xb = (b * 32 + j) * 16384;
    const float* mrow = maskf + (b * 32 + j) * 64;
    float* outA = out + FUSED_N + ((size_t)((b * 32 + i) * 32 + j)) * 4096;

    const f32x4 z = {0.f, 0.f, 0.f, 0.f};

#pragma unroll 1
    for (int nh = 0; nh < 2; ++nh) {       // ng half: columns nh*32..nh*32+31
        f32x4 acc[4][2];
#pragma unroll
        for (int rg = 0; rg < 4; ++rg)
#pragma unroll
            for (int ngl = 0; ngl < 2; ++ngl) acc[rg][ngl] = z;

#pragma unroll
        for (int k0 = 0; k0 < 8; ++k0) {
            bf16x8 Bh[2], Bl[2];
#pragma unroll
            for (int ngl = 0; ngl < 2; ++ngl) {
                const int bo = xb + ((nh * 2 + ngl) * 16 + m) * 256 + k0 * 32 + quad * 8;
                Bh[ngl] = *(const bf16x8*)&XhG[bo];
                Bl[ngl] = *(const bf16x8*)&XlG[bo];
            }
            bf16x8 Ahk[4], Alk[4];
#pragma unroll
            for (int rg = 0; rg < 4; ++rg) {
                const int o = (rg * 16 + m) * 256 + (((k0 * 4 + quad) ^ m)) * 8;
                Ahk[rg] = *(const bf16x8*)&sPh[o];
                Alk[rg] = *(const bf16x8*)&sPl[o];
            }
#pragma unroll
            for (int rg = 0; rg < 4; ++rg)
#pragma unroll
                for (int ngl = 0; ngl < 2; ++ngl) {
                    acc[rg][ngl] = __builtin_amdgcn_mfma_f32_16x16x32_bf16(Ahk[rg], Bh[ngl], acc[rg][ngl], 0, 0, 0);
                    acc[rg][ngl] = __builtin_amdgcn_mfma_f32_16x16x32_bf16(Ahk[rg], Bl[ngl], acc[rg][ngl], 0, 0, 0);
                    acc[rg][ngl] = __builtin_amdgcn_mfma_f32_16x16x32_bf16(Alk[rg], Bh[ngl], acc[rg][ngl], 0, 0, 0);
                }
        }

        // ---- wave-local epilogue for this ng half ----
        float madd[2];
#pragma unroll
        for (int ngl = 0; ngl < 2; ++ngl)
            madd[ngl] = (1.0f - mrow[(nh * 2 + ngl) * 16 + m]) * NEG_BIG;

        float part[2] = {0.f, 0.f};
#pragma unroll
        for (int rg = 0; rg < 4; ++rg)
#pragma unroll
            for (int r = 0; r < 4; ++r) {
                const int s = rg * 16 + quad * 4 + r;
                const float as_ = sAs[s];
#pragma unroll
                for (int ngl = 0; ngl < 2; ++ngl) {
                    float x = acc[rg][ngl][r] + madd[ngl];
                    float a = 1.0f / (1.0f + __expf(-x));
                    outA[s * 64 + (nh * 2 + ngl) * 16 + m] = a;
                    part[ngl] += as_ * a;
                }
            }
#pragma unroll
        for (int ngl = 0; ngl < 2; ++ngl) {  // reduce over quad (t = .. + m)
            part[ngl] += __shfl_xor(part[ngl], 16, 64);
            part[ngl] += __shfl_xor(part[ngl], 32, 64);
        }
        if (quad == 0) {
#pragma unroll
            for (int ngl = 0; ngl < 2; ++ngl)
                sW[wave][(nh * 2 + ngl) * 16 + m] = part[ngl];
        }
    }

    // Within-wave LDS write->read: in-order, lgkmcnt-protected; no barrier.
    const float* Xg = Xf + xb;
    float4 acf = {0.f, 0.f, 0.f, 0.f};
#pragma unroll 8
    for (int t = 0; t < 64; ++t) {
        const float wv = sW[wave][t];
        float4 xv = *(const float4*)&Xg[t * 256 + lane * 4];
        acf.x += wv * xv.x;
        acf.y += wv * xv.y;
        acf.z += wv * xv.z;
        acf.w += wv * xv.w;
    }
    *(float4*)&out[((size_t)((b * 32 + i) * 32 + j)) * 256 + lane * 4] = acf;
}

extern "C" void kernel_launch(void* const* d_in, const int* in_sizes, int n_in,
                              void* d_out, int out_size, void* d_ws, size_t ws_size,
                              hipStream_t stream) {
    const float* X     = (const float*)d_in[0];  // [4,32,64,256] fp32
    const float* mask  = (const float*)d_in[1];  // [4,32,64]
    const float* aself = (const float*)d_in[2];  // [4,32,64]
    const float* W     = (const float*)d_in[3];  // [256,256]
    float* out = (float*)d_out;

    __bf16* ws = (__bf16*)d_ws;
    const size_t NX = 2097152, NW = 65536;
    __bf16* Xh = ws;
    __bf16* Xl = Xh + NX;
    __bf16* Ph = Xl + NX;
    __bf16* Pl = Ph + NX;
    __bf16* Wh = Pl + NX;
    __bf16* Wl = Wh + NW;

    convw_kernel<<<dim3(64), dim3(256), 0, stream>>>(W, Wh, Wl);
    prep_kernel<<<dim3(512), dim3(256), 0, stream>>>(X, Wh, Wl, Xh, Xl, Ph, Pl);
    main_kernel<<<dim3(512), dim3(512), 0, stream>>>(
        X, mask, aself, Xh, Xl, Ph, Pl, out);
}

// Round 5
// 182.128 us; speedup vs baseline: 1.0403x; 1.0403x over previous
//
#include <hip/hip_runtime.h>
#include <hip/hip_bf16.h>

typedef __bf16 bf16x8 __attribute__((ext_vector_type(8)));
typedef float  f32x4  __attribute__((ext_vector_type(4)));

#define NEG_BIG (-1e10f)

constexpr int FUSED_N = 4 * 32 * 32 * 256;  // 1048576

// ---------------------------------------------------------------------------
// fp32 inputs, no fp32 MFMA on CDNA4: split x = hi + lo (bf16 RNE + residual),
// scores ~= Ah*Bh + Ah*Bl + Al*Bh (drop lo*lo). Verified r2-r5.
// r3/r5 lesson: spill tripwire = WRITE_SIZE above the exact 69,636 KB floor.
// r5 lesson: total-minus-main ~90 us is fixed harness overhead.
// r6 lesson: each async_ld16 covers 2 rows; 64 rows = 32 insts.
// r8: capping allocator (launch_bounds or unroll-1) -> spill, NOT occupancy.
// r10 rule (r0-r4, 5 data points): waves/SIMD = floor(512/combined arch+AGPR),
//   block-granular. 4 waves/SIMD needs combined <=128 NATURALLY.
//     r0 172->2w | r1 128->4w(spilled) | r2 148->2w | r3 156->2w
//     r4 unroll-1: compiler kept pipeline wide -> 104MB scratch, 101us.
// r11 (this round): shrink the PER-WAVE TILE structurally. Wave = (j, s-half):
//   acc[2][4]=32 AGPR, A-frags 16, B-frags 32 -> ~80 live + ~20 addr ≈ 102
//   combined <= 128 with margin, no allocator games. Grid 1024 = (b,i,jh),
//   8 waves = 4 j x 2 s-halves. LDS unchanged -> 2 blocks/CU -> 16 waves/CU.
//   Fused GEMV: partial w per s-half -> sW, barrier, pair combines, h-split.
// ---------------------------------------------------------------------------

// Async 16B global->LDS (DMA). Lane L lands at wave-uniform base + 16*L.
__device__ __forceinline__ void async_ld16(const void* g, void* l) {
    __builtin_amdgcn_global_load_lds(
        (const __attribute__((address_space(1))) void*)g,
        (__attribute__((address_space(3))) void*)l, 16, 0, 0);
}

// 16row x 32granule (16x256 bf16) tile for prep.
__device__ __forceinline__ int swzp(int row, int g) {
    return (row * 32 + (g ^ row)) * 8;   // row in [0,16)
}

// W fp32 -> hi/lo bf16 planes. 64 blocks x 256 threads x 4 elems.
__global__ __launch_bounds__(256) void convw_kernel(
    const float* __restrict__ W, __bf16* __restrict__ Wh, __bf16* __restrict__ Wl) {
    int idx = blockIdx.x * 256 + threadIdx.x;  // 0..16383
    float4 v = ((const float4*)W)[idx];
    float f[4] = {v.x, v.y, v.z, v.w};
    union { __bf16 b[4]; uint2 u; } H, L;
#pragma unroll
    for (int k = 0; k < 4; ++k) {
        __bf16 h = (__bf16)f[k];
        H.b[k] = h;
        L.b[k] = (__bf16)(f[k] - (float)h);
    }
    *(uint2*)&Wh[idx * 4] = H.u;
    *(uint2*)&Wl[idx * 4] = L.u;
}

// ---------------------------------------------------------------------------
// prep: convert 16 X rows -> Xh/Xl planes (global + LDS) and compute
// P = X @ W^T (split-3) -> Ph/Pl. 512 blocks; wave w handles col group w.
// ---------------------------------------------------------------------------
__global__ __launch_bounds__(256, 2) void prep_kernel(
    const float* __restrict__ Xf,
    const __bf16* __restrict__ Wh, const __bf16* __restrict__ Wl,
    __bf16* __restrict__ XhG, __bf16* __restrict__ XlG,
    __bf16* __restrict__ Ph, __bf16* __restrict__ Pl) {
    __shared__ __align__(16) __bf16 sXh[16 * 256];   // 8 KB
    __shared__ __align__(16) __bf16 sXl[16 * 256];   // 8 KB
    const int tid = threadIdx.x, rb = blockIdx.x;    // rows rb*16..rb*16+15

#pragma unroll
    for (int it = 0; it < 2; ++it) {
        int idx = it * 256 + tid;          // 512 granules
        int row = idx >> 5, g = idx & 31;
        const float* p = Xf + (rb * 16 + row) * 256 + g * 8;
        float4 v0 = *(const float4*)p;
        float4 v1 = *(const float4*)(p + 4);
        float f[8] = {v0.x, v0.y, v0.z, v0.w, v1.x, v1.y, v1.z, v1.w};
        union { __bf16 b[8]; uint4 u; } H, L;
#pragma unroll
        for (int k = 0; k < 8; ++k) {
            __bf16 h = (__bf16)f[k];
            H.b[k] = h;
            L.b[k] = (__bf16)(f[k] - (float)h);
        }
        int go = (rb * 16 + row) * 256 + g * 8;
        *(uint4*)&XhG[go] = H.u;
        *(uint4*)&XlG[go] = L.u;
        int o = swzp(row, g);
        *(uint4*)&sXh[o] = H.u;
        *(uint4*)&sXl[o] = L.u;
    }
    __syncthreads();

    const int lane = tid & 63, wave = tid >> 6, m = lane & 15, quad = lane >> 4;
    bf16x8 Ah[8], Al[8];
#pragma unroll
    for (int k0 = 0; k0 < 8; ++k0) {
        int o = swzp(m, k0 * 4 + quad);
        Ah[k0] = *(const bf16x8*)&sXh[o];
        Al[k0] = *(const bf16x8*)&sXl[o];
    }
    f32x4 acc[4];
    const f32x4 z = {0.f, 0.f, 0.f, 0.f};
#pragma unroll
    for (int n = 0; n < 4; ++n) acc[n] = z;
#pragma unroll
    for (int k0 = 0; k0 < 8; ++k0) {
#pragma unroll
        for (int n = 0; n < 4; ++n) {
            const int gcol = wave * 64 + n * 16 + m;
            const int wo = gcol * 256 + k0 * 32 + quad * 8;
            bf16x8 bh = *(const bf16x8*)&Wh[wo];
            bf16x8 bl = *(const bf16x8*)&Wl[wo];
            acc[n] = __builtin_amdgcn_mfma_f32_16x16x32_bf16(Ah[k0], bh, acc[n], 0, 0, 0);
            acc[n] = __builtin_amdgcn_mfma_f32_16x16x32_bf16(Ah[k0], bl, acc[n], 0, 0, 0);
            acc[n] = __builtin_amdgcn_mfma_f32_16x16x32_bf16(Al[k0], bh, acc[n], 0, 0, 0);
        }
    }
#pragma unroll
    for (int n = 0; n < 4; ++n)
#pragma unroll
        for (int r = 0; r < 4; ++r) {
            int row = rb * 16 + quad * 4 + r;
            int col = wave * 64 + n * 16 + m;
            float v = acc[n][r];
            __bf16 h = (__bf16)v;
            Ph[row * 256 + col] = h;
            Pl[row * 256 + col] = (__bf16)(v - (float)h);
        }
}

// ---------------------------------------------------------------------------
// main: 1024 blocks = (b, i, jh), 512 threads = 8 waves = 4 j x 2 s-halves.
// Stage P(b,i) hi/lo (64 KB, swizzled) via async DMA; barrier; wave w
// computes the 32x64 score half-tile for j = jh*4 + (w&3), s-rows
// [(w>>2)*32, +32). acc[2][4] = 32 AGPR keeps combined regs ~102 <= 128 ->
// 2 blocks/CU x 8 waves = 16 waves/CU (4/SIMD). B frags stream from global
// (L2-hot); A frags from LDS. Epilogue: sigmoid+att store wave-local;
// partial w -> sW; barrier; the (jw, jw+4) pair combines w and splits the
// fused GEMV by h-half (float2 per lane).
// ---------------------------------------------------------------------------
__global__ __launch_bounds__(512, 2) void main_kernel(
    const float* __restrict__ Xf, const float* __restrict__ maskf,
    const float* __restrict__ aselff,
    const __bf16* __restrict__ XhG, const __bf16* __restrict__ XlG,
    const __bf16* __restrict__ PhG, const __bf16* __restrict__ PlG,
    float* __restrict__ out) {
    __shared__ __align__(16) __bf16 sPh[64 * 256];   // 32 KB
    __shared__ __align__(16) __bf16 sPl[64 * 256];   // 32 KB
    __shared__ float sW[8][64];                      // 2 KB, per-wave partial w
    __shared__ float sAs[64];                        // 256 B, aself row (i)
    const int tid = threadIdx.x;
    const int jh = blockIdx.x & 7;
    const int i  = (blockIdx.x >> 3) & 31;
    const int b  = blockIdx.x >> 8;
    const int lane = tid & 63, wave = tid >> 6, m = lane & 15, quad = lane >> 4;

    // Stage P(b,i) hi/lo. Each inst covers rows 2*insti..+1 (64 lanes x 16B);
    // 64 rows = 32 insts = 4 per wave. Slot (row,gs) gets granule gs^(row&15).
    const int pbase = (b * 32 + i) * 16384;
    {
        const int rowhalf = lane >> 5;     // 0..1
        const int gslot = lane & 31;
#pragma unroll
        for (int it = 0; it < 4; ++it) {
            const int insti = wave * 4 + it;           // 0..31
            const int row = insti * 2 + rowhalf;       // 0..63
            const int g = gslot ^ (row & 15);
            const int src = pbase + row * 256 + g * 8;
            async_ld16(&PhG[src], &sPh[insti * 512]);
            async_ld16(&PlG[src], &sPl[insti * 512]);
        }
    }

    // aself row for block-constant i -> LDS (broadcast reads in epilogue).
    if (tid < 64) sAs[tid] = aselff[(b * 32 + i) * 64 + tid];

    __syncthreads();   // DMA drained

    const int jw = wave & 3, sh = wave >> 2;
    const int j  = jh * 4 + jw;
    const int xb = (b * 32 + j) * 16384;

    f32x4 acc[2][4];
    const f32x4 z = {0.f, 0.f, 0.f, 0.f};
#pragma unroll
    for (int rg = 0; rg < 2; ++rg)
#pragma unroll
        for (int ng = 0; ng < 4; ++ng) acc[rg][ng] = z;

#pragma unroll
    for (int k0 = 0; k0 < 8; ++k0) {
        bf16x8 Bh[4], Bl[4];
#pragma unroll
        for (int ng = 0; ng < 4; ++ng) {
            const int bo = xb + (ng * 16 + m) * 256 + k0 * 32 + quad * 8;
            Bh[ng] = *(const bf16x8*)&XhG[bo];
            Bl[ng] = *(const bf16x8*)&XlG[bo];
        }
        bf16x8 Ahk[2], Alk[2];
#pragma unroll
        for (int rg = 0; rg < 2; ++rg) {
            const int row = sh * 32 + rg * 16 + m;     // row&15 == m
            const int o = row * 256 + (((k0 * 4 + quad) ^ m)) * 8;
            Ahk[rg] = *(const bf16x8*)&sPh[o];
            Alk[rg] = *(const bf16x8*)&sPl[o];
        }
#pragma unroll
        for (int rg = 0; rg < 2; ++rg)
#pragma unroll
            for (int ng = 0; ng < 4; ++ng) {
                acc[rg][ng] = __builtin_amdgcn_mfma_f32_16x16x32_bf16(Ahk[rg], Bh[ng], acc[rg][ng], 0, 0, 0);
                acc[rg][ng] = __builtin_amdgcn_mfma_f32_16x16x32_bf16(Ahk[rg], Bl[ng], acc[rg][ng], 0, 0, 0);
                acc[rg][ng] = __builtin_amdgcn_mfma_f32_16x16x32_bf16(Alk[rg], Bh[ng], acc[rg][ng], 0, 0, 0);
            }
    }

    // ---- wave-local epilogue: sigmoid + att store + partial w ----
    const float* mrow = maskf + (b * 32 + j) * 64;
    float madd[4];
#pragma unroll
    for (int ng = 0; ng < 4; ++ng)
        madd[ng] = (1.0f - mrow[ng * 16 + m]) * NEG_BIG;

    float part[4] = {0.f, 0.f, 0.f, 0.f};
    float* outA = out + FUSED_N + ((size_t)((b * 32 + i) * 32 + j)) * 4096;
#pragma unroll
    for (int rg = 0; rg < 2; ++rg)
#pragma unroll
        for (int r = 0; r < 4; ++r) {
            const int s = sh * 32 + rg * 16 + quad * 4 + r;
            const float as_ = sAs[s];
#pragma unroll
            for (int ng = 0; ng < 4; ++ng) {
                float x = acc[rg][ng][r] + madd[ng];
                float a = 1.0f / (1.0f + __expf(-x));
                outA[s * 64 + ng * 16 + m] = a;
                part[ng] += as_ * a;
            }
        }
#pragma unroll
    for (int ng = 0; ng < 4; ++ng) {   // reduce over quad (t = ng*16+m)
        part[ng] += __shfl_xor(part[ng], 16, 64);
        part[ng] += __shfl_xor(part[ng], 32, 64);
    }
    if (quad == 0) {
#pragma unroll
        for (int ng = 0; ng < 4; ++ng) sW[wave][ng * 16 + m] = part[ng];
    }

    __syncthreads();   // cross-wave: partial w ready

    // ---- fused GEMV: pair (jw, jw+4) shares j; this wave does h-half sh ----
    const float* Xg = Xf + xb;
    const int hbase = sh * 128 + lane * 2;
    float a0 = 0.f, a1 = 0.f;
#pragma unroll 8
    for (int t = 0; t < 64; ++t) {
        const float wv = sW[jw][t] + sW[jw + 4][t];
        const float2 xv = *(const float2*)&Xg[t * 256 + hbase];
        a0 += wv * xv.x;
        a1 += wv * xv.y;
    }
    float2 res = {a0, a1};
    *(float2*)&out[((size_t)((b * 32 + i) * 32 + j)) * 256 + hbase] = res;
}

extern "C" void kernel_launch(void* const* d_in, const int* in_sizes, int n_in,
                              void* d_out, int out_size, void* d_ws, size_t ws_size,
                              hipStream_t stream) {
    const float* X     = (const float*)d_in[0];  // [4,32,64,256] fp32
    const float* mask  = (const float*)d_in[1];  // [4,32,64]
    const float* aself = (const float*)d_in[2];  // [4,32,64]
    const float* W     = (const float*)d_in[3];  // [256,256]
    float* out = (float*)d_out;

    __bf16* ws = (__bf16*)d_ws;
    const size_t NX = 2097152, NW = 65536;
    __bf16* Xh = ws;
    __bf16* Xl = Xh + NX;
    __bf16* Ph = Xl + NX;
    __bf16* Pl = Ph + NX;
    __bf16* Wh = Pl + NX;
    __bf16* Wl = Wh + NW;

    convw_kernel<<<dim3(64), dim3(256), 0, stream>>>(W, Wh, Wl);
    prep_kernel<<<dim3(512), dim3(256), 0, stream>>>(X, Wh, Wl, Xh, Xl, Ph, Pl);
    main_kernel<<<dim3(1024), dim3(512), 0, stream>>>(
        X, mask, aself, Xh, Xl, Ph, Pl, out);
}

// Round 6
// 149.980 us; speedup vs baseline: 1.2632x; 1.2143x over previous
//
#include <hip/hip_runtime.h>
#include <hip/hip_bf16.h>

typedef __bf16 bf16x8 __attribute__((ext_vector_type(8)));
typedef float  f32x4  __attribute__((ext_vector_type(4)));

#define NEG_BIG (-1e10f)

constexpr int FUSED_N = 4 * 32 * 32 * 256;  // 1048576

// ---------------------------------------------------------------------------
// fp32 inputs, no fp32 MFMA on CDNA4: split x = hi + lo (bf16 RNE + residual),
// scores ~= Ah*Bh + Ah*Bl + Al*Bh (drop lo*lo). Verified r2-r5.
// r3/r5 lesson: spill tripwire = WRITE_SIZE above the exact 69,636 KB floor.
// r5 lesson: total-minus-main ~90 us is fixed harness overhead.
// r6 lesson: each async_ld16 covers 2 rows; 64 rows = 32 insts.
// r8: capping the allocator (launch_bounds/unroll-1) -> spill, not occupancy.
// r10 rule (confirmed by r11): waves/SIMD = floor(512 / combined VGPR+AGPR),
//   block-granular. r11 hit 88 combined -> 39% occupancy, NO spill...
// r11 lesson: ...and got SLOWER (94 vs 60 us; MfmaUtil 10.5, VALU 16.6).
//   Occupancy is NOT the binding constraint. Halving MFMA/wave kept
//   B-loads/wave constant -> 2x total VMEM insts, all pipes idler.
//   VGPR_Count=56 shows the scheduler put loads next to uses: ZERO MLP;
//   every k0 serializes on a ~300-500cy L2/L3 round trip.
// r12 (this round): max work/wave (acc[4][4], 48 MFMA per 8-load set,
//   8 waves x one full j tile) + EXPLICIT pipelining:
//   - rotating 2-bank register prefetch of B(k0+1) issued before k0's MFMAs
//     (first set issued BEFORE __syncthreads to overlap the DMA drain);
//   - sched_group_barrier per phase (8 VMEM_READ -> 8 DS_READ -> 48 MFMA)
//     to pin the interleave the r5 scheduler refused to produce.
//   ~185 combined regs -> 1 block/CU (2 waves/SIMD) by design.
// ---------------------------------------------------------------------------

// Async 16B global->LDS (DMA). Lane L lands at wave-uniform base + 16*L.
__device__ __forceinline__ void async_ld16(const void* g, void* l) {
    __builtin_amdgcn_global_load_lds(
        (const __attribute__((address_space(1))) void*)g,
        (__attribute__((address_space(3))) void*)l, 16, 0, 0);
}

// 16row x 32granule (16x256 bf16) tile for prep.
__device__ __forceinline__ int swzp(int row, int g) {
    return (row * 32 + (g ^ row)) * 8;   // row in [0,16)
}

// W fp32 -> hi/lo bf16 planes. 64 blocks x 256 threads x 4 elems.
__global__ __launch_bounds__(256) void convw_kernel(
    const float* __restrict__ W, __bf16* __restrict__ Wh, __bf16* __restrict__ Wl) {
    int idx = blockIdx.x * 256 + threadIdx.x;  // 0..16383
    float4 v = ((const float4*)W)[idx];
    float f[4] = {v.x, v.y, v.z, v.w};
    union { __bf16 b[4]; uint2 u; } H, L;
#pragma unroll
    for (int k = 0; k < 4; ++k) {
        __bf16 h = (__bf16)f[k];
        H.b[k] = h;
        L.b[k] = (__bf16)(f[k] - (float)h);
    }
    *(uint2*)&Wh[idx * 4] = H.u;
    *(uint2*)&Wl[idx * 4] = L.u;
}

// ---------------------------------------------------------------------------
// prep: convert 16 X rows -> Xh/Xl planes (global + LDS) and compute
// P = X @ W^T (split-3) -> Ph/Pl. 512 blocks; wave w handles col group w.
// ---------------------------------------------------------------------------
__global__ __launch_bounds__(256, 2) void prep_kernel(
    const float* __restrict__ Xf,
    const __bf16* __restrict__ Wh, const __bf16* __restrict__ Wl,
    __bf16* __restrict__ XhG, __bf16* __restrict__ XlG,
    __bf16* __restrict__ Ph, __bf16* __restrict__ Pl) {
    __shared__ __align__(16) __bf16 sXh[16 * 256];   // 8 KB
    __shared__ __align__(16) __bf16 sXl[16 * 256];   // 8 KB
    const int tid = threadIdx.x, rb = blockIdx.x;    // rows rb*16..rb*16+15

#pragma unroll
    for (int it = 0; it < 2; ++it) {
        int idx = it * 256 + tid;          // 512 granules
        int row = idx >> 5, g = idx & 31;
        const float* p = Xf + (rb * 16 + row) * 256 + g * 8;
        float4 v0 = *(const float4*)p;
        float4 v1 = *(const float4*)(p + 4);
        float f[8] = {v0.x, v0.y, v0.z, v0.w, v1.x, v1.y, v1.z, v1.w};
        union { __bf16 b[8]; uint4 u; } H, L;
#pragma unroll
        for (int k = 0; k < 8; ++k) {
            __bf16 h = (__bf16)f[k];
            H.b[k] = h;
            L.b[k] = (__bf16)(f[k] - (float)h);
        }
        int go = (rb * 16 + row) * 256 + g * 8;
        *(uint4*)&XhG[go] = H.u;
        *(uint4*)&XlG[go] = L.u;
        int o = swzp(row, g);
        *(uint4*)&sXh[o] = H.u;
        *(uint4*)&sXl[o] = L.u;
    }
    __syncthreads();

    const int lane = tid & 63, wave = tid >> 6, m = lane & 15, quad = lane >> 4;
    bf16x8 Ah[8], Al[8];
#pragma unroll
    for (int k0 = 0; k0 < 8; ++k0) {
        int o = swzp(m, k0 * 4 + quad);
        Ah[k0] = *(const bf16x8*)&sXh[o];
        Al[k0] = *(const bf16x8*)&sXl[o];
    }
    f32x4 acc[4];
    const f32x4 z = {0.f, 0.f, 0.f, 0.f};
#pragma unroll
    for (int n = 0; n < 4; ++n) acc[n] = z;
#pragma unroll
    for (int k0 = 0; k0 < 8; ++k0) {
#pragma unroll
        for (int n = 0; n < 4; ++n) {
            const int gcol = wave * 64 + n * 16 + m;
            const int wo = gcol * 256 + k0 * 32 + quad * 8;
            bf16x8 bh = *(const bf16x8*)&Wh[wo];
            bf16x8 bl = *(const bf16x8*)&Wl[wo];
            acc[n] = __builtin_amdgcn_mfma_f32_16x16x32_bf16(Ah[k0], bh, acc[n], 0, 0, 0);
            acc[n] = __builtin_amdgcn_mfma_f32_16x16x32_bf16(Ah[k0], bl, acc[n], 0, 0, 0);
            acc[n] = __builtin_amdgcn_mfma_f32_16x16x32_bf16(Al[k0], bh, acc[n], 0, 0, 0);
        }
    }
#pragma unroll
    for (int n = 0; n < 4; ++n)
#pragma unroll
        for (int r = 0; r < 4; ++r) {
            int row = rb * 16 + quad * 4 + r;
            int col = wave * 64 + n * 16 + m;
            float v = acc[n][r];
            __bf16 h = (__bf16)v;
            Ph[row * 256 + col] = h;
            Pl[row * 256 + col] = (__bf16)(v - (float)h);
        }
}

// ---------------------------------------------------------------------------
// main: 512 blocks = (b, i, jq), 512 threads = 8 waves, one j per wave.
// Stage P(b,i) hi/lo (64 KB, swizzled) via async DMA; the first B-load set
// issues BEFORE the barrier; after it, each wave runs an 8-phase k0 pipeline:
//   phase k: issue B(k+1) into the spare bank, read A(k) from LDS,
//            sched_group_barrier pins {8 VMEM_READ, 8 DS_READ, 48 MFMA},
//            MFMA set consumes B(k) from the current bank.
// Epilogue (sigmoid, att store, w-reduce, fused GEMV) is wave-local.
// ~185 combined regs -> 1 block/CU; per-wave ILP (not occupancy) hides latency.
// ---------------------------------------------------------------------------
__global__ __launch_bounds__(512, 2) void main_kernel(
    const float* __restrict__ Xf, const float* __restrict__ maskf,
    const float* __restrict__ aselff,
    const __bf16* __restrict__ XhG, const __bf16* __restrict__ XlG,
    const __bf16* __restrict__ PhG, const __bf16* __restrict__ PlG,
    float* __restrict__ out) {
    __shared__ __align__(16) __bf16 sPh[64 * 256];   // 32 KB
    __shared__ __align__(16) __bf16 sPl[64 * 256];   // 32 KB
    __shared__ float sW[8][64];                      // 2 KB, wave-private rows
    __shared__ float sAs[64];                        // 256 B, aself row (i)
    const int tid = threadIdx.x;
    const int jq = blockIdx.x & 3;
    const int i  = (blockIdx.x >> 2) & 31;
    const int b  = blockIdx.x >> 7;
    const int lane = tid & 63, wave = tid >> 6, m = lane & 15, quad = lane >> 4;

    // Stage P(b,i) hi/lo. Each inst covers rows 2*insti..+1 (64 lanes x 16B);
    // 64 rows = 32 insts = 4 per wave. Slot (row,gs) gets granule gs^(row&15).
    const int pbase = (b * 32 + i) * 16384;
    {
        const int rowhalf = lane >> 5;     // 0..1
        const int gslot = lane & 31;
#pragma unroll
        for (int it = 0; it < 4; ++it) {
            const int insti = wave * 4 + it;           // 0..31
            const int row = insti * 2 + rowhalf;       // 0..63
            const int g = gslot ^ (row & 15);
            const int src = pbase + row * 256 + g * 8;
            async_ld16(&PhG[src], &sPh[insti * 512]);
            async_ld16(&PlG[src], &sPl[insti * 512]);
        }
    }

    // aself row for block-constant i -> LDS (broadcast reads in epilogue).
    if (tid < 64) sAs[tid] = aselff[(b * 32 + i) * 64 + tid];

    const int j = jq * 8 + wave;
    const int xb = (b * 32 + j) * 16384;

#define LOADB(KC, BH, BL)                                                     \
    do {                                                                      \
        _Pragma("unroll")                                                     \
        for (int ng = 0; ng < 4; ++ng) {                                      \
            const int bo = xb + (ng * 16 + m) * 256 + (KC) * 32 + quad * 8;   \
            BH[ng] = *(const bf16x8*)&XhG[bo];                                \
            BL[ng] = *(const bf16x8*)&XlG[bo];                                \
        }                                                                     \
    } while (0)

#define LOADA(KC)                                                             \
    do {                                                                      \
        _Pragma("unroll")                                                     \
        for (int rg = 0; rg < 4; ++rg) {                                      \
            const int o = (rg * 16 + m) * 256 + ((((KC) * 4 + quad)) ^ m) * 8;\
            Ah[rg] = *(const bf16x8*)&sPh[o];                                 \
            Al[rg] = *(const bf16x8*)&sPl[o];                                 \
        }                                                                     \
    } while (0)

#define MFMASET(BH, BL)                                                       \
    do {                                                                      \
        _Pragma("unroll")                                                     \
        for (int rg = 0; rg < 4; ++rg)                                        \
            _Pragma("unroll")                                                 \
            for (int ng = 0; ng < 4; ++ng) {                                  \
                acc[rg][ng] = __builtin_amdgcn_mfma_f32_16x16x32_bf16(        \
                    Ah[rg], BH[ng], acc[rg][ng], 0, 0, 0);                    \
                acc[rg][ng] = __builtin_amdgcn_mfma_f32_16x16x32_bf16(        \
                    Ah[rg], BL[ng], acc[rg][ng], 0, 0, 0);                    \
                acc[rg][ng] = __builtin_amdgcn_mfma_f32_16x16x32_bf16(        \
                    Al[rg], BH[ng], acc[rg][ng], 0, 0, 0);                    \
            }                                                                 \
    } while (0)

// phase KC: consume BHc/BLc, prefetch KC+1 into BHn/BLn (if LOADNEXT).
// SGB pins: 8 global loads, then 8 ds_reads, then 48 MFMAs per phase.
#define PHASE(KC, BHc, BLc, BHn, BLn, LOADNEXT)                               \
    do {                                                                      \
        if (LOADNEXT) {                                                       \
            LOADB((KC) + 1, BHn, BLn);                                        \
            __builtin_amdgcn_sched_group_barrier(0x20, 8, 0);  /*VMEM_READ*/  \
        }                                                                     \
        LOADA(KC);                                                            \
        __builtin_amdgcn_sched_group_barrier(0x100, 8, 0);     /*DS_READ*/    \
        __builtin_amdgcn_sched_group_barrier(0x8, 48, 0);      /*MFMA*/       \
        MFMASET(BHc, BLc);                                                    \
    } while (0)

    bf16x8 Bh0[4], Bl0[4], Bh1[4], Bl1[4];
    bf16x8 Ah[4], Al[4];

    LOADB(0, Bh0, Bl0);   // pre-barrier: overlaps the DMA drain

    __syncthreads();      // DMA drained; the ONLY barrier

    f32x4 acc[4][4];
    const f32x4 z = {0.f, 0.f, 0.f, 0.f};
#pragma unroll
    for (int rg = 0; rg < 4; ++rg)
#pragma unroll
        for (int ng = 0; ng < 4; ++ng) acc[rg][ng] = z;

    PHASE(0, Bh0, Bl0, Bh1, Bl1, true);
    PHASE(1, Bh1, Bl1, Bh0, Bl0, true);
    PHASE(2, Bh0, Bl0, Bh1, Bl1, true);
    PHASE(3, Bh1, Bl1, Bh0, Bl0, true);
    PHASE(4, Bh0, Bl0, Bh1, Bl1, true);
    PHASE(5, Bh1, Bl1, Bh0, Bl0, true);
    PHASE(6, Bh0, Bl0, Bh1, Bl1, true);
    PHASE(7, Bh1, Bl1, Bh0, Bl0, false);

#undef PHASE
#undef MFMASET
#undef LOADA
#undef LOADB

    // ---- wave-local epilogue ----
    const float* mrow = maskf + (b * 32 + j) * 64;
    float madd[4];
#pragma unroll
    for (int ng = 0; ng < 4; ++ng)
        madd[ng] = (1.0f - mrow[ng * 16 + m]) * NEG_BIG;

    float part[4] = {0.f, 0.f, 0.f, 0.f};
    float* outA = out + FUSED_N + ((size_t)((b * 32 + i) * 32 + j)) * 4096;
#pragma unroll
    for (int rg = 0; rg < 4; ++rg)
#pragma unroll
        for (int r = 0; r < 4; ++r) {
            const int s = rg * 16 + quad * 4 + r;
            const float as_ = sAs[s];
#pragma unroll
            for (int ng = 0; ng < 4; ++ng) {
                float x = acc[rg][ng][r] + madd[ng];
                float a = 1.0f / (1.0f + __expf(-x));
                outA[s * 64 + ng * 16 + m] = a;
                part[ng] += as_ * a;
            }
        }
#pragma unroll
    for (int ng = 0; ng < 4; ++ng) {   // reduce over quad (t = ng*16+m)
        part[ng] += __shfl_xor(part[ng], 16, 64);
        part[ng] += __shfl_xor(part[ng], 32, 64);
    }
    if (quad == 0) {
#pragma unroll
        for (int ng = 0; ng < 4; ++ng) sW[wave][ng * 16 + m] = part[ng];
    }
    // Within-wave LDS write->read: in-order, lgkmcnt-protected; no barrier.
    const float* Xg = Xf + xb;
    float4 acf = {0.f, 0.f, 0.f, 0.f};
#pragma unroll 8
    for (int t = 0; t < 64; ++t) {
        const float wv = sW[wave][t];
        float4 xv = *(const float4*)&Xg[t * 256 + lane * 4];
        acf.x += wv * xv.x;
        acf.y += wv * xv.y;
        acf.z += wv * xv.z;
        acf.w += wv * xv.w;
    }
    *(float4*)&out[((size_t)((b * 32 + i) * 32 + j)) * 256 + lane * 4] = acf;
}

extern "C" void kernel_launch(void* const* d_in, const int* in_sizes, int n_in,
                              void* d_out, int out_size, void* d_ws, size_t ws_size,
                              hipStream_t stream) {
    const float* X     = (const float*)d_in[0];  // [4,32,64,256] fp32
    const float* mask  = (const float*)d_in[1];  // [4,32,64]
    const float* aself = (const float*)d_in[2];  // [4,32,64]
    const float* W     = (const float*)d_in[3];  // [256,256]
    float* out = (float*)d_out;

    __bf16* ws = (__bf16*)d_ws;
    const size_t NX = 2097152, NW = 65536;
    __bf16* Xh = ws;
    __bf16* Xl = Xh + NX;
    __bf16* Ph = Xl + NX;
    __bf16* Pl = Ph + NX;
    __bf16* Wh = Pl + NX;
    __bf16* Wl = Wh + NW;

    convw_kernel<<<dim3(64), dim3(256), 0, stream>>>(W, Wh, Wl);
    prep_kernel<<<dim3(512), dim3(256), 0, stream>>>(X, Wh, Wl, Xh, Xl, Ph, Pl);
    main_kernel<<<dim3(512), dim3(512), 0, stream>>>(
        X, mask, aself, Xh, Xl, Ph, Pl, out);
}

// Round 7
// 149.506 us; speedup vs baseline: 1.2672x; 1.0032x over previous
//
#include <hip/hip_runtime.h>
#include <hip/hip_bf16.h>

typedef __bf16 bf16x8 __attribute__((ext_vector_type(8)));
typedef float  f32x4  __attribute__((ext_vector_type(4)));
typedef float  f32x16 __attribute__((ext_vector_type(16)));

#define NEG_BIG (-1e10f)

constexpr int FUSED_N = 4 * 32 * 32 * 256;  // 1048576

// ---------------------------------------------------------------------------
// fp32 inputs, no fp32 MFMA on CDNA4: split x = hi + lo (bf16 RNE + residual),
// scores ~= Ah*Bh + Ah*Bl + Al*Bh (drop lo*lo). Verified r2-r5.
// r3/r5 lesson: spill tripwire = WRITE_SIZE above the exact 69,636 KB floor.
// r5 lesson: total-minus-main ~90 us is fixed harness overhead.
// r10 rule (r0-r5, 6 pts): waves/SIMD = floor(512 / combined VGPR+AGPR),
//   block-granular. (512,4) = combined cap 128 (r1: arch 64 + agpr 64).
// r11: 39% occupancy via half-tiles -> SLOWER (2x VMEM insts). Work/wave
//   must stay maximal.
// r12/r6 lesson: source-level prefetch banks + sched_group_barrier get
//   re-narrowed by the allocator (VGPR 76 < the 96+ the rotation needs);
//   3 failed rounds of source pipelining. Cross-wave overlap is the only
//   robust latency hider -> need combined <=128 NATURALLY at FULL tile.
// r13 (this round): switch to mfma_f32_32x32x16_bf16. Same 64x64 tile,
//   same acc floor (4 x f32x16 = 64 AGPR), but per-chunk frag live-set is
//   32 regs (A[2]+B[2] hi/lo bf16x8) vs 96 for the 16x16 shape. Natural
//   combined ~110 <= 128 -> (512,4) caps WITHOUT spill -> 2 blocks/CU =
//   4 waves/SIMD at full work/wave. 24 MFMA x 8cyc per K=32 x 4 waves
//   covers ~200cyc L2 latency with zero explicit pipelining. Half the
//   MFMA/ds/VMEM instruction count of the 16x16 version.
//   C/D: col=l&31, row=(r&3)+8*(r>>2)+4*(l>>5) [guide m74/m101].
// ---------------------------------------------------------------------------

// Async 16B global->LDS (DMA). Lane L lands at wave-uniform base + 16*L.
__device__ __forceinline__ void async_ld16(const void* g, void* l) {
    __builtin_amdgcn_global_load_lds(
        (const __attribute__((address_space(1))) void*)g,
        (__attribute__((address_space(3))) void*)l, 16, 0, 0);
}

// 16row x 32granule (16x256 bf16) tile for prep.
__device__ __forceinline__ int swzp(int row, int g) {
    return (row * 32 + (g ^ row)) * 8;   // row in [0,16)
}

// W fp32 -> hi/lo bf16 planes. 64 blocks x 256 threads x 4 elems.
__global__ __launch_bounds__(256) void convw_kernel(
    const float* __restrict__ W, __bf16* __restrict__ Wh, __bf16* __restrict__ Wl) {
    int idx = blockIdx.x * 256 + threadIdx.x;  // 0..16383
    float4 v = ((const float4*)W)[idx];
    float f[4] = {v.x, v.y, v.z, v.w};
    union { __bf16 b[4]; uint2 u; } H, L;
#pragma unroll
    for (int k = 0; k < 4; ++k) {
        __bf16 h = (__bf16)f[k];
        H.b[k] = h;
        L.b[k] = (__bf16)(f[k] - (float)h);
    }
    *(uint2*)&Wh[idx * 4] = H.u;
    *(uint2*)&Wl[idx * 4] = L.u;
}

// ---------------------------------------------------------------------------
// prep: convert 16 X rows -> Xh/Xl planes (global + LDS) and compute
// P = X @ W^T (split-3) -> Ph/Pl. 512 blocks; wave w handles col group w.
// ---------------------------------------------------------------------------
__global__ __launch_bounds__(256, 2) void prep_kernel(
    const float* __restrict__ Xf,
    const __bf16* __restrict__ Wh, const __bf16* __restrict__ Wl,
    __bf16* __restrict__ XhG, __bf16* __restrict__ XlG,
    __bf16* __restrict__ Ph, __bf16* __restrict__ Pl) {
    __shared__ __align__(16) __bf16 sXh[16 * 256];   // 8 KB
    __shared__ __align__(16) __bf16 sXl[16 * 256];   // 8 KB
    const int tid = threadIdx.x, rb = blockIdx.x;    // rows rb*16..rb*16+15

#pragma unroll
    for (int it = 0; it < 2; ++it) {
        int idx = it * 256 + tid;          // 512 granules
        int row = idx >> 5, g = idx & 31;
        const float* p = Xf + (rb * 16 + row) * 256 + g * 8;
        float4 v0 = *(const float4*)p;
        float4 v1 = *(const float4*)(p + 4);
        float f[8] = {v0.x, v0.y, v0.z, v0.w, v1.x, v1.y, v1.z, v1.w};
        union { __bf16 b[8]; uint4 u; } H, L;
#pragma unroll
        for (int k = 0; k < 8; ++k) {
            __bf16 h = (__bf16)f[k];
            H.b[k] = h;
            L.b[k] = (__bf16)(f[k] - (float)h);
        }
        int go = (rb * 16 + row) * 256 + g * 8;
        *(uint4*)&XhG[go] = H.u;
        *(uint4*)&XlG[go] = L.u;
        int o = swzp(row, g);
        *(uint4*)&sXh[o] = H.u;
        *(uint4*)&sXl[o] = L.u;
    }
    __syncthreads();

    const int lane = tid & 63, wave = tid >> 6, m = lane & 15, quad = lane >> 4;
    bf16x8 Ah[8], Al[8];
#pragma unroll
    for (int k0 = 0; k0 < 8; ++k0) {
        int o = swzp(m, k0 * 4 + quad);
        Ah[k0] = *(const bf16x8*)&sXh[o];
        Al[k0] = *(const bf16x8*)&sXl[o];
    }
    f32x4 acc[4];
    const f32x4 z = {0.f, 0.f, 0.f, 0.f};
#pragma unroll
    for (int n = 0; n < 4; ++n) acc[n] = z;
#pragma unroll
    for (int k0 = 0; k0 < 8; ++k0) {
#pragma unroll
        for (int n = 0; n < 4; ++n) {
            const int gcol = wave * 64 + n * 16 + m;
            const int wo = gcol * 256 + k0 * 32 + quad * 8;
            bf16x8 bh = *(const bf16x8*)&Wh[wo];
            bf16x8 bl = *(const bf16x8*)&Wl[wo];
            acc[n] = __builtin_amdgcn_mfma_f32_16x16x32_bf16(Ah[k0], bh, acc[n], 0, 0, 0);
            acc[n] = __builtin_amdgcn_mfma_f32_16x16x32_bf16(Ah[k0], bl, acc[n], 0, 0, 0);
            acc[n] = __builtin_amdgcn_mfma_f32_16x16x32_bf16(Al[k0], bh, acc[n], 0, 0, 0);
        }
    }
#pragma unroll
    for (int n = 0; n < 4; ++n)
#pragma unroll
        for (int r = 0; r < 4; ++r) {
            int row = rb * 16 + quad * 4 + r;
            int col = wave * 64 + n * 16 + m;
            float v = acc[n][r];
            __bf16 h = (__bf16)v;
            Ph[row * 256 + col] = h;
            Pl[row * 256 + col] = (__bf16)(v - (float)h);
        }
}

// ---------------------------------------------------------------------------
// main: 512 blocks = (b, i, jq), 512 threads = 8 waves, one j per wave.
// Stage P(b,i) hi/lo (64 KB, swizzled) via async DMA; ONE barrier; each wave
// runs 16 K-chunks (K=16) of 32x32x16 MFMAs: per chunk 4 B-loads (global,
// L2-hot) + 4 A ds_reads + 12 MFMAs into acc[2][2] f32x16 (64 AGPR).
// Frag live-set 32 arch regs -> combined ~110 <= 128 under (512,4) cap ->
// 2 blocks/CU = 4 waves/SIMD; cross-wave overlap hides load latency.
// Epilogue wave-local; aself row in LDS; fused GEMV unchanged.
// ---------------------------------------------------------------------------
__global__ __launch_bounds__(512, 4) void main_kernel(
    const float* __restrict__ Xf, const float* __restrict__ maskf,
    const float* __restrict__ aselff,
    const __bf16* __restrict__ XhG, const __bf16* __restrict__ XlG,
    const __bf16* __restrict__ PhG, const __bf16* __restrict__ PlG,
    float* __restrict__ out) {
    __shared__ __align__(16) __bf16 sPh[64 * 256];   // 32 KB
    __shared__ __align__(16) __bf16 sPl[64 * 256];   // 32 KB
    __shared__ float sW[8][64];                      // 2 KB, wave-private rows
    __shared__ float sAs[64];                        // 256 B, aself row (i)
    const int tid = threadIdx.x;
    const int jq = blockIdx.x & 3;
    const int i  = (blockIdx.x >> 2) & 31;
    const int b  = blockIdx.x >> 7;
    const int lane = tid & 63, wave = tid >> 6;
    const int c31 = lane & 31, hi = lane >> 5, m15 = lane & 15;

    // Stage P(b,i) hi/lo. Each inst covers rows 2*insti..+1 (64 lanes x 16B);
    // 64 rows = 32 insts = 4 per wave. Slot (row,gs) gets granule gs^(row&15).
    const int pbase = (b * 32 + i) * 16384;
    {
        const int rowhalf = lane >> 5;     // 0..1
        const int gslot = lane & 31;
#pragma unroll
        for (int it = 0; it < 4; ++it) {
            const int insti = wave * 4 + it;           // 0..31
            const int row = insti * 2 + rowhalf;       // 0..63
            const int g = gslot ^ (row & 15);
            const int src = pbase + row * 256 + g * 8;
            async_ld16(&PhG[src], &sPh[insti * 512]);
            async_ld16(&PlG[src], &sPl[insti * 512]);
        }
    }

    // aself row for block-constant i -> LDS (broadcast reads in epilogue).
    if (tid < 64) sAs[tid] = aselff[(b * 32 + i) * 64 + tid];

    __syncthreads();   // DMA drained; the ONLY barrier

    const int j = jq * 8 + wave;
    const int xb = (b * 32 + j) * 16384;

    // B-frag (32x32x16): lane holds X[t = ng*32 + c31, h = kc*16 + hi*8 + e].
    const int boff = xb + c31 * 256 + hi * 8;
    // A-frag: lane holds P[s = rg*32 + c31, h = kc*16 + hi*8 + e] from
    // swizzled LDS: granule gg = kc*2 + hi lives at slot gg^(c31&15).
    const int arow0 = c31 * 256;          // rg=0 row base (elements)
    const int arow1 = (32 + c31) * 256;   // rg=1

    f32x16 acc00, acc01, acc10, acc11;
#pragma unroll
    for (int e = 0; e < 16; ++e) { acc00[e] = 0.f; acc01[e] = 0.f; acc10[e] = 0.f; acc11[e] = 0.f; }

#pragma unroll
    for (int kc = 0; kc < 16; ++kc) {
        bf16x8 Bh0 = *(const bf16x8*)&XhG[boff + kc * 16];
        bf16x8 Bh1 = *(const bf16x8*)&XhG[boff + 32 * 256 + kc * 16];
        bf16x8 Bl0 = *(const bf16x8*)&XlG[boff + kc * 16];
        bf16x8 Bl1 = *(const bf16x8*)&XlG[boff + 32 * 256 + kc * 16];
        const int slot = ((kc * 2 + hi) ^ m15) * 8;
        bf16x8 Ah0 = *(const bf16x8*)&sPh[arow0 + slot];
        bf16x8 Ah1 = *(const bf16x8*)&sPh[arow1 + slot];
        bf16x8 Al0 = *(const bf16x8*)&sPl[arow0 + slot];
        bf16x8 Al1 = *(const bf16x8*)&sPl[arow1 + slot];

        acc00 = __builtin_amdgcn_mfma_f32_32x32x16_bf16(Ah0, Bh0, acc00, 0, 0, 0);
        acc00 = __builtin_amdgcn_mfma_f32_32x32x16_bf16(Ah0, Bl0, acc00, 0, 0, 0);
        acc00 = __builtin_amdgcn_mfma_f32_32x32x16_bf16(Al0, Bh0, acc00, 0, 0, 0);
        acc01 = __builtin_amdgcn_mfma_f32_32x32x16_bf16(Ah0, Bh1, acc01, 0, 0, 0);
        acc01 = __builtin_amdgcn_mfma_f32_32x32x16_bf16(Ah0, Bl1, acc01, 0, 0, 0);
        acc01 = __builtin_amdgcn_mfma_f32_32x32x16_bf16(Al0, Bh1, acc01, 0, 0, 0);
        acc10 = __builtin_amdgcn_mfma_f32_32x32x16_bf16(Ah1, Bh0, acc10, 0, 0, 0);
        acc10 = __builtin_amdgcn_mfma_f32_32x32x16_bf16(Ah1, Bl0, acc10, 0, 0, 0);
        acc10 = __builtin_amdgcn_mfma_f32_32x32x16_bf16(Al1, Bh0, acc10, 0, 0, 0);
        acc11 = __builtin_amdgcn_mfma_f32_32x32x16_bf16(Ah1, Bh1, acc11, 0, 0, 0);
        acc11 = __builtin_amdgcn_mfma_f32_32x32x16_bf16(Ah1, Bl1, acc11, 0, 0, 0);
        acc11 = __builtin_amdgcn_mfma_f32_32x32x16_bf16(Al1, Bh1, acc11, 0, 0, 0);
    }

    // ---- wave-local epilogue ----
    // C/D: col t = ng*32 + c31; row s = rg*32 + (r&3) + 8*(r>>2) + 4*hi.
    const float* mrow = maskf + (b * 32 + j) * 64;
    float madd[2];
#pragma unroll
    for (int ng = 0; ng < 2; ++ng)
        madd[ng] = (1.0f - mrow[ng * 32 + c31]) * NEG_BIG;

    float part[2] = {0.f, 0.f};
    float* outA = out + FUSED_N + ((size_t)((b * 32 + i) * 32 + j)) * 4096;
#pragma unroll
    for (int rg = 0; rg < 2; ++rg)
#pragma unroll
        for (int r = 0; r < 16; ++r) {
            const int s = rg * 32 + (r & 3) + 8 * (r >> 2) + 4 * hi;
            const float as_ = sAs[s];
            const float a0v = (rg == 0) ? acc00[r] : acc10[r];
            const float a1v = (rg == 0) ? acc01[r] : acc11[r];
            {
                float x = a0v + madd[0];
                float a = 1.0f / (1.0f + __expf(-x));
                outA[s * 64 + c31] = a;
                part[0] += as_ * a;
            }
            {
                float x = a1v + madd[1];
                float a = 1.0f / (1.0f + __expf(-x));
                outA[s * 64 + 32 + c31] = a;
                part[1] += as_ * a;
            }
        }
    // reduce over the two k-halves (lanes l and l^32 share t = c31)
    part[0] += __shfl_xor(part[0], 32, 64);
    part[1] += __shfl_xor(part[1], 32, 64);
    if (hi == 0) {
        sW[wave][c31] = part[0];
        sW[wave][32 + c31] = part[1];
    }
    // Within-wave LDS write->read: in-order, lgkmcnt-protected; no barrier.
    const float* Xg = Xf + xb;
    float4 acf = {0.f, 0.f, 0.f, 0.f};
#pragma unroll 8
    for (int t = 0; t < 64; ++t) {
        const float wv = sW[wave][t];
        float4 xv = *(const float4*)&Xg[t * 256 + lane * 4];
        acf.x += wv * xv.x;
        acf.y += wv * xv.y;
        acf.z += wv * xv.z;
        acf.w += wv * xv.w;
    }
    *(float4*)&out[((size_t)((b * 32 + i) * 32 + j)) * 256 + lane * 4] = acf;
}

extern "C" void kernel_launch(void* const* d_in, const int* in_sizes, int n_in,
                              void* d_out, int out_size, void* d_ws, size_t ws_size,
                              hipStream_t stream) {
    const float* X     = (const float*)d_in[0];  // [4,32,64,256] fp32
    const float* mask  = (const float*)d_in[1];  // [4,32,64]
    const float* aself = (const float*)d_in[2];  // [4,32,64]
    const float* W     = (const float*)d_in[3];  // [256,256]
    float* out = (float*)d_out;

    __bf16* ws = (__bf16*)d_ws;
    const size_t NX = 2097152, NW = 65536;
    __bf16* Xh = ws;
    __bf16* Xl = Xh + NX;
    __bf16* Ph = Xl + NX;
    __bf16* Pl = Ph + NX;
    __bf16* Wh = Pl + NX;
    __bf16* Wl = Wh + NW;

    convw_kernel<<<dim3(64), dim3(256), 0, stream>>>(W, Wh, Wl);
    prep_kernel<<<dim3(512), dim3(256), 0, stream>>>(X, Wh, Wl, Xh, Xl, Ph, Pl);
    main_kernel<<<dim3(512), dim3(512), 0, stream>>>(
        X, mask, aself, Xh, Xl, Ph, Pl, out);
}